// Round 8
// baseline (461.259 us; speedup 1.0000x reference)
//
#include <hip/hip_runtime.h>
#include <math.h>

#define NPIX 16384
#define CH 256
#define MDIM 32
#define NB 8
#define EPSF 1e-6f
#define SPLIT 16
#define KCH (NPIX / SPLIT)   // 1024

// ws BYTE layout
//   ATTB @ 0        : bf16 attn [B][C][D]  1,048,576 B
//   KVTB @ 1048576  : bf16 KV^T [B][C][M]    131,072 B
//   KSUM @ 1179648  : f32 [B][M]               1,024 B
//   XKR  @ 1180672  : f32 [B][M][D]          262,144 B
//   WQH  @ 1442816  : bf16 [M][C] 16384 B   (hi split of wq)
//   WQL  @ 1459200  : bf16 [M][C] 16384 B
//   WKH  @ 1475584  : bf16 [M][C] 16384 B
//   WKL  @ 1491968  : bf16 [M][C] 16384 B
// d_out doubles as scratch before k_final overwrites it (stream-ordered):
//   [0, 16777216) floats          xkpart [B][T=256][M][D=256]
//   [16777216, 25165824) floats   enpart [SPLIT=16][B][C][C]
#define XKPART_SZ 16777216ull

typedef short short8 __attribute__((ext_vector_type(8)));
typedef float f32x4 __attribute__((ext_vector_type(4)));

__device__ inline unsigned short f2bf(float v) {
    unsigned u = __builtin_bit_cast(unsigned, v);
    unsigned r = u + 0x7FFFu + ((u >> 16) & 1u);   // RNE (finite inputs)
    return (unsigned short)(r >> 16);
}
__device__ inline float bf2f(unsigned short h) {
    unsigned u = (unsigned)h << 16;
    return __builtin_bit_cast(float, u);
}

// Pre-split wq/wk into hi/lo bf16 pairs.
__global__ void k_prep(const float* __restrict__ wq, const float* __restrict__ wk,
                       unsigned short* __restrict__ WQH, unsigned short* __restrict__ WQL,
                       unsigned short* __restrict__ WKH, unsigned short* __restrict__ WKL)
{
    int i = blockIdx.x * 256 + threadIdx.x;   // 8192 total
    float q = wq[i], k = wk[i];
    unsigned short qh = f2bf(q);
    WQH[i] = qh; WQL[i] = f2bf(q - bf2f(qh));
    unsigned short kh = f2bf(k);
    WKH[i] = kh; WKL[i] = f2bf(k - bf2f(kh));
}

// Single-staging k_kx (unchanged from round 7).
__global__ __launch_bounds__(256, 4) void k_kx(
    const float* __restrict__ x,
    const unsigned short* __restrict__ WKH, const unsigned short* __restrict__ WKL,
    const float* __restrict__ bk,
    float* __restrict__ xkpart, float* __restrict__ Ksum)
{
    __shared__ unsigned short xs[CH * 72];     // 36 KB bf16 x tile [d][64n + hash pad]
    __shared__ unsigned short ksm[MDIM * 72];  // 4.5 KB bf16 softplus(K) [m][n]
    const int b = blockIdx.y, t = blockIdx.x, n0 = t * 64, tid = threadIdx.x;
    const int w = tid >> 6, l = tid & 63;
    const int li = l & 15, lg = l >> 4;
    const float* xb = x + (size_t)b * CH * NPIX;

    #pragma unroll
    for (int s = 0; s < 8; ++s) {
        int e8 = tid + s * 256;
        int c = e8 >> 3, j8 = e8 & 7;
        const float* src = xb + (size_t)c * NPIX + n0 + j8 * 8;
        float4 v0 = *(const float4*)src;
        float4 v1 = *(const float4*)(src + 4);
        float vv[8] = {v0.x, v0.y, v0.z, v0.w, v1.x, v1.y, v1.z, v1.w};
        short8 p;
        #pragma unroll
        for (int e = 0; e < 8; ++e) p[e] = (short)f2bf(vv[e]);
        const int g = j8 ^ (c & 7) ^ ((c >> 3) & 7);
        *(short8*)&xs[c * 72 + g * 8] = p;
    }
    __syncthreads();

    {   // K via MFMA; wave w covers n = w*16 + li
        f32x4 accq[2];
        accq[0] = (f32x4){0.f, 0.f, 0.f, 0.f};
        accq[1] = (f32x4){0.f, 0.f, 0.f, 0.f};
        const int n = w * 16 + li;
        const int gn = n >> 3, inn = n & 7;
        #pragma unroll
        for (int kc = 0; kc < 8; ++kc) {
            short8 bxw;
            #pragma unroll
            for (int e = 0; e < 8; ++e) {
                const int d = kc * 32 + lg * 8 + e;
                const int g = gn ^ e ^ ((kc * 4 + lg) & 7);
                bxw[e] = (short)xs[d * 72 + g * 8 + inn];
            }
            #pragma unroll
            for (int i = 0; i < 2; ++i) {
                short8 wh = *(const short8*)(WKH + (size_t)(i * 16 + li) * CH + kc * 32 + lg * 8);
                short8 wl = *(const short8*)(WKL + (size_t)(i * 16 + li) * CH + kc * 32 + lg * 8);
                accq[i] = __builtin_amdgcn_mfma_f32_16x16x32_bf16(wh, bxw, accq[i], 0, 0, 0);
                accq[i] = __builtin_amdgcn_mfma_f32_16x16x32_bf16(wl, bxw, accq[i], 0, 0, 0);
            }
        }
        #pragma unroll
        for (int i = 0; i < 2; ++i)
            #pragma unroll
            for (int q = 0; q < 4; ++q) {
                const int m = i * 16 + lg * 4 + q;
                float kv = accq[i][q] + bk[m];
                kv = fmaxf(kv, 0.f) + log1pf(expf(-fabsf(kv)));  // softplus
                ksm[m * 72 + (n ^ ((m & 7) << 3))] = f2bf(kv);
            }
    }
    __syncthreads();

    if (tid < MDIM) {
        float s = 0.f;
        #pragma unroll
        for (int j = 0; j < 64; ++j)
            s += bf2f(ksm[tid * 72 + (j ^ ((tid & 7) << 3))]);
        atomicAdd(&Ksum[b * MDIM + tid], s);
    }

    f32x4 axk[4][2];
    #pragma unroll
    for (int i = 0; i < 4; ++i)
        #pragma unroll
        for (int j = 0; j < 2; ++j) axk[i][j] = (f32x4){0.f, 0.f, 0.f, 0.f};

    #pragma unroll
    for (int ks2 = 0; ks2 < 2; ++ks2) {
        const int nc = ks2 * 32 + lg * 8;
        short8 kfr[2];
        #pragma unroll
        for (int j = 0; j < 2; ++j) {
            const int m = j * 16 + li;
            kfr[j] = *(const short8*)&ksm[m * 72 + (nc ^ ((m & 7) << 3))];
        }
        #pragma unroll
        for (int i = 0; i < 4; ++i) {
            const int d = w * 64 + i * 16 + li;
            const int g = (nc >> 3) ^ (d & 7) ^ ((d >> 3) & 7);
            short8 xf = *(const short8*)&xs[d * 72 + g * 8];
            #pragma unroll
            for (int j = 0; j < 2; ++j)
                axk[i][j] = __builtin_amdgcn_mfma_f32_16x16x32_bf16(kfr[j], xf, axk[i][j], 0, 0, 0);
        }
    }

    __syncthreads();
    float* xsF = (float*)xs;
    #pragma unroll
    for (int i = 0; i < 4; ++i)
        #pragma unroll
        for (int j = 0; j < 2; ++j)
            #pragma unroll
            for (int q = 0; q < 4; ++q) {
                const int m = j * 16 + lg * 4 + q;
                const int d = w * 64 + i * 16 + li;
                xsF[m * 256 + (d ^ ((m & 7) << 2))] = axk[i][j][q];
            }
    __syncthreads();
    float* xp = xkpart + (size_t)(b * 256 + t) * MDIM * CH;
    #pragma unroll 4
    for (int m = 0; m < MDIM; ++m)
        xp[m * CH + tid] = xsF[m * 256 + (tid ^ ((m & 7) << 2))];
}

__global__ void k_xkreduce(const float* __restrict__ xkpart, float* __restrict__ XKR) {
    const int b = blockIdx.x >> 5, m = blockIdx.x & 31, d = threadIdx.x;
    float s = 0.f;
    #pragma unroll 4
    for (int t = 0; t < 256; ++t)
        s += xkpart[(((size_t)b * 256 + t) * MDIM + m) * CH + d];
    XKR[((size_t)b * MDIM + m) * CH + d] = s;
}

// KV^T[c][m] (bf16) = sum_d wv[c][d]*XKR[m][d] + bv[c]*Ksum[m]
__global__ void k_kv(const float* __restrict__ wv, const float* __restrict__ bv,
                     const float* __restrict__ XKR, const float* __restrict__ Ksum,
                     unsigned short* __restrict__ KVTb) {
    const int b = blockIdx.x, q = blockIdx.y;
    const int ci = threadIdx.x & 63, mg = threadIdx.x >> 6;
    const int c = q * 64 + ci;
    float s[8];
    const float bvc = bv[c];
    #pragma unroll
    for (int i = 0; i < 8; ++i) s[i] = bvc * Ksum[b * MDIM + mg * 8 + i];
    #pragma unroll 4
    for (int d = 0; d < CH; ++d) {
        float w = wv[(size_t)c * CH + d];
        #pragma unroll
        for (int i = 0; i < 8; ++i)
            s[i] = fmaf(w, XKR[((size_t)b * MDIM + mg * 8 + i) * CH + d], s[i]);
    }
    short8 p;
    #pragma unroll
    for (int i = 0; i < 8; ++i) p[i] = (short)f2bf(s[i]);
    *(short8*)(KVTb + ((size_t)b * CH + c) * MDIM + mg * 8) = p;
}

// Gram via split-bf16 MFMA, symmetry-aware (SPLIT=16).
__global__ __launch_bounds__(256, 2) void k_gram(const float* __restrict__ x,
                                                 float* __restrict__ enpart)
{
    __shared__ unsigned short lds[4 * 128 * 72];
    unsigned short* Ah = lds;
    unsigned short* Al = lds + 128 * 72;
    unsigned short* Bh = lds + 2 * 128 * 72;
    unsigned short* Bl = lds + 3 * 128 * 72;

    const int tid = threadIdx.x;
    const int rt = (blockIdx.x == 2) ? 1 : 0;
    const int ct = (blockIdx.x == 0) ? 0 : 1;
    const bool diag = (rt == ct);
    const int sp = blockIdx.y, b = blockIdx.z;
    const int r0 = rt * 128, c0 = ct * 128;
    const float* xb = x + (size_t)b * CH * NPIX;
    const int k0base = sp * KCH;

    unsigned short* Bh_p = diag ? Ah : Bh;
    unsigned short* Bl_p = diag ? Al : Bl;

    const int wave = tid >> 6, lane = tid & 63;
    const int wr = wave >> 1, wc = wave & 1;

    f32x4 acc[4][4];
    #pragma unroll
    for (int i = 0; i < 4; ++i)
        #pragma unroll
        for (int j = 0; j < 4; ++j)
            acc[i][j] = (f32x4){0.f, 0.f, 0.f, 0.f};

    const int oct = tid & 7;
    const int frow = tid >> 3;

    for (int kk = 0; kk < KCH; kk += 64) {
        __syncthreads();
        const int k0 = k0base + kk;
        #pragma unroll
        for (int half = 0; half < 2; ++half) {
            if (half && diag) continue;
            const int rowbase = half ? c0 : r0;
            unsigned short* Hh = half ? Bh : Ah;
            unsigned short* Hl = half ? Bl : Al;
            #pragma unroll
            for (int s = 0; s < 4; ++s) {
                const int r = frow + s * 32;
                const float* src = xb + (size_t)(rowbase + r) * NPIX + k0 + oct * 8;
                float4 v0 = *(const float4*)src;
                float4 v1 = *(const float4*)(src + 4);
                float vv[8] = {v0.x, v0.y, v0.z, v0.w, v1.x, v1.y, v1.z, v1.w};
                short8 ph, pl;
                #pragma unroll
                for (int e = 0; e < 8; ++e) {
                    unsigned short h = f2bf(vv[e]);
                    unsigned short l = f2bf(vv[e] - bf2f(h));
                    ph[e] = (short)h;
                    pl[e] = (short)l;
                }
                *(short8*)&Hh[r * 72 + oct * 8] = ph;
                *(short8*)&Hl[r * 72 + oct * 8] = pl;
            }
        }
        __syncthreads();

        #pragma unroll
        for (int ks2 = 0; ks2 < 2; ++ks2) {
            short8 ah[4], al[4], bh[4], bl[4];
            const int rbase = wr * 64 + (lane & 15);
            const int cbase = wc * 64 + (lane & 15);
            const int koff = ks2 * 32 + (lane >> 4) * 8;
            #pragma unroll
            for (int f = 0; f < 4; ++f) {
                ah[f] = *(const short8*)&Ah[(rbase + f * 16) * 72 + koff];
                al[f] = *(const short8*)&Al[(rbase + f * 16) * 72 + koff];
                bh[f] = *(const short8*)&Bh_p[(cbase + f * 16) * 72 + koff];
                bl[f] = *(const short8*)&Bl_p[(cbase + f * 16) * 72 + koff];
            }
            #pragma unroll
            for (int i = 0; i < 4; ++i)
                #pragma unroll
                for (int j = 0; j < 4; ++j) {
                    acc[i][j] = __builtin_amdgcn_mfma_f32_16x16x32_bf16(ah[i], bh[j], acc[i][j], 0, 0, 0);
                    acc[i][j] = __builtin_amdgcn_mfma_f32_16x16x32_bf16(ah[i], bl[j], acc[i][j], 0, 0, 0);
                    acc[i][j] = __builtin_amdgcn_mfma_f32_16x16x32_bf16(al[i], bh[j], acc[i][j], 0, 0, 0);
                }
        }
    }

    float* ep = enpart + (size_t)(sp * NB + b) * (CH * CH);
    const int rw = (lane >> 4) * 4;
    const int cw = lane & 15;
    #pragma unroll
    for (int i = 0; i < 4; ++i)
        #pragma unroll
        for (int j = 0; j < 4; ++j) {
            const int row = r0 + wr * 64 + i * 16 + rw;
            const int col = c0 + wc * 64 + j * 16 + cw;
            #pragma unroll
            for (int q = 0; q < 4; ++q) {
                float v = acc[i][j][q];
                ep[(size_t)(row + q) * CH + col] = v;
                if (!diag) ep[(size_t)col * CH + (row + q)] = v;
            }
        }
}

// softmin over summed partials; emits bf16 attn [b][c][d].
__global__ void k_softmax(const float* __restrict__ enpart,
                          unsigned short* __restrict__ attnb) {
    const int b = blockIdx.x >> 8, c = blockIdx.x & 255;
    const int d = threadIdx.x;
    __shared__ float red[8];
    float e = 0.f;
    #pragma unroll
    for (int sp = 0; sp < SPLIT; ++sp)
        e += enpart[(size_t)(sp * NB + b) * (CH * CH) + (size_t)c * CH + d];
    float mn = e;
    #pragma unroll
    for (int o = 1; o < 64; o <<= 1) mn = fminf(mn, __shfl_xor(mn, o));
    if ((d & 63) == 0) red[d >> 6] = mn;
    __syncthreads();
    mn = fminf(fminf(red[0], red[1]), fminf(red[2], red[3]));
    float w = expf(mn - e);
    float s = w;
    #pragma unroll
    for (int o = 1; o < 64; o <<= 1) s += __shfl_xor(s, o);
    if ((d & 63) == 0) red[4 + (d >> 6)] = s;
    __syncthreads();
    s = red[4] + red[5] + red[6] + red[7];
    attnb[((size_t)(b * CH) + c) * CH + d] = f2bf(w / s);
}

// out = x + gk*norm*(KV^T·Q) + gc*(attn·X), Q inline via MFMA.
// Two c-half passes (unroll 1) halve live accumulators (128->64 regs) so
// 3 blocks/CU fit (was 2: VGPR+AGPR ~240/wave).  launch_bounds(256,3).
__global__ __launch_bounds__(256, 3) void k_final(
    const float* __restrict__ x,
    const unsigned short* __restrict__ WQH, const unsigned short* __restrict__ WQL,
    const float* __restrict__ bq,
    const unsigned short* __restrict__ KVTb, const float* __restrict__ Ksum,
    const unsigned short* __restrict__ attnb, const float* __restrict__ gk,
    const float* __restrict__ gc, float* __restrict__ out)
{
    __shared__ uint2 xsTv[4096];            // 32 KB: bf16 xT [n=64][d=256] swizzled
    __shared__ unsigned short qsT[64 * 40]; // 5 KB: bf16 Q [n][m] (pad 40)
    __shared__ float den_s[64];
    unsigned char* xsT = (unsigned char*)xsTv;
    const int b = blockIdx.y, n0 = blockIdx.x * 64, tid = threadIdx.x;
    const int w = tid >> 6, l = tid & 63;
    const int li = l & 15, lg = l >> 4;
    const float* xb = x + (size_t)b * CH * NPIX;

    // ---- stage xT ----
    {
        const int n4 = li * 4;
        const bool o1 = lg & 1, o2 = (lg >> 1) & 1;
        #pragma unroll
        for (int p = 0; p < 16; ++p) {
            const int d0 = w * 64 + p * 4;
            float4 vv = *(const float4*)(xb + (size_t)(d0 + lg) * NPIX + n0 + n4);
            float v0 = vv.x, v1 = vv.y, v2 = vv.z, v3 = vv.w;
            float r1 = __shfl_xor(o1 ? v0 : v1, 16);
            float r2 = __shfl_xor(o1 ? v2 : v3, 16);
            float a0 = o1 ? r1 : v0, a1 = o1 ? v1 : r1;
            float a2 = o1 ? r2 : v2, a3 = o1 ? v3 : r2;
            float r3 = __shfl_xor(o2 ? a0 : a2, 32);
            float r4 = __shfl_xor(o2 ? a1 : a3, 32);
            float b0 = o2 ? r3 : a0, b1 = o2 ? r4 : a1;
            float b2 = o2 ? a2 : r3, b3 = o2 ? a3 : r4;
            const int nl = n4 + lg;
            unsigned lo = (unsigned)f2bf(b0) | ((unsigned)f2bf(b1) << 16);
            unsigned hi = (unsigned)f2bf(b2) | ((unsigned)f2bf(b3) << 16);
            const int off = nl * 512 +
                ((2 * d0) ^ ((nl & 7) << 4) ^ (((nl >> 3) & 1) << 3));
            *(uint2*)(xsT + off) = make_uint2(lo, hi);
        }
    }
    __syncthreads();

    // ---- inline Q via MFMA ----
    {
        f32x4 accq[2];
        accq[0] = (f32x4){0.f, 0.f, 0.f, 0.f};
        accq[1] = (f32x4){0.f, 0.f, 0.f, 0.f};
        const int nf = w * 16 + li;
        const int sw = ((nf & 7) << 4) ^ (((nf >> 3) & 1) << 3);
        #pragma unroll
        for (int kc = 0; kc < 8; ++kc) {
            const int d2 = 2 * (kc * 32 + lg * 8);
            uint2 h0 = *(const uint2*)(xsT + nf * 512 + (d2 ^ sw));
            uint2 h1 = *(const uint2*)(xsT + nf * 512 + ((d2 + 8) ^ sw));
            int4 tmp = make_int4(h0.x, h0.y, h1.x, h1.y);
            short8 bxw = __builtin_bit_cast(short8, tmp);
            #pragma unroll
            for (int i = 0; i < 2; ++i) {
                short8 wh = *(const short8*)(WQH + (size_t)(i * 16 + li) * CH + kc * 32 + lg * 8);
                short8 wl = *(const short8*)(WQL + (size_t)(i * 16 + li) * CH + kc * 32 + lg * 8);
                accq[i] = __builtin_amdgcn_mfma_f32_16x16x32_bf16(wh, bxw, accq[i], 0, 0, 0);
                accq[i] = __builtin_amdgcn_mfma_f32_16x16x32_bf16(wl, bxw, accq[i], 0, 0, 0);
            }
        }
        float den = 0.f;
        #pragma unroll
        for (int i = 0; i < 2; ++i)
            #pragma unroll
            for (int q = 0; q < 4; ++q) {
                const int m = i * 16 + lg * 4 + q;
                float qv = accq[i][q] + bq[m];
                qv = fmaxf(qv, 0.f) + log1pf(expf(-fabsf(qv)));  // softplus
                qsT[(w * 16 + li) * 40 + m] = f2bf(qv);
                den = fmaf(qv, Ksum[b * MDIM + m] + EPSF, den);
            }
        den += __shfl_xor(den, 16);
        den += __shfl_xor(den, 32);
        if (lg == 0) den_s[w * 16 + li] = gk[0] / den;
    }
    __syncthreads();

    // ---- hoisted per-thread operands ----
    short8 qb[4];
    #pragma unroll
    for (int j = 0; j < 4; ++j)
        qb[j] = *(const short8*)&qsT[(j * 16 + li) * 40 + lg * 8];
    float nrm[4];
    #pragma unroll
    for (int j = 0; j < 4; ++j) nrm[j] = den_s[j * 16 + li];
    const float gcv = gc[0];
    const unsigned short* ab = attnb + (size_t)b * CH * CH;

    // ---- two c-half passes: KAM + CAM + epilogue for c in [w*64+ih*32, +32) ----
    #pragma unroll 1
    for (int ih = 0; ih < 2; ++ih) {
        f32x4 acc[2][4], accP[2][4];
        #pragma unroll
        for (int ii = 0; ii < 2; ++ii)
            #pragma unroll
            for (int j = 0; j < 4; ++j) {
                acc[ii][j] = (f32x4){0.f, 0.f, 0.f, 0.f};
                accP[ii][j] = (f32x4){0.f, 0.f, 0.f, 0.f};
            }

        // KAM: P = KV^T · Q for this c-half
        #pragma unroll
        for (int ii = 0; ii < 2; ++ii) {
            short8 ka = *(const short8*)(KVTb +
                ((size_t)b * CH + w * 64 + (ih * 2 + ii) * 16 + li) * MDIM + lg * 8);
            #pragma unroll
            for (int j = 0; j < 4; ++j)
                accP[ii][j] = __builtin_amdgcn_mfma_f32_16x16x32_bf16(ka, qb[j], accP[ii][j], 0, 0, 0);
        }

        // CAM: attn · X for this c-half
        for (int kk = 0; kk < CH; kk += 32) {
            short8 bx[4];
            #pragma unroll
            for (int j = 0; j < 4; ++j) {
                const int nf = j * 16 + li;
                const int d2 = 2 * (kk + lg * 8);
                const int sw = ((nf & 7) << 4) ^ (((nf >> 3) & 1) << 3);
                uint2 h0 = *(const uint2*)(xsT + nf * 512 + (d2 ^ sw));
                uint2 h1 = *(const uint2*)(xsT + nf * 512 + ((d2 + 8) ^ sw));
                int4 tmp = make_int4(h0.x, h0.y, h1.x, h1.y);
                bx[j] = __builtin_bit_cast(short8, tmp);
            }
            #pragma unroll
            for (int ii = 0; ii < 2; ++ii) {
                short8 af = *(const short8*)(ab +
                    (size_t)(w * 64 + (ih * 2 + ii) * 16 + li) * CH + kk + lg * 8);
                #pragma unroll
                for (int j = 0; j < 4; ++j)
                    acc[ii][j] = __builtin_amdgcn_mfma_f32_16x16x32_bf16(af, bx[j], acc[ii][j], 0, 0, 0);
            }
        }

        // epilogue for this c-half
        #pragma unroll
        for (int ii = 0; ii < 2; ++ii)
            #pragma unroll
            for (int j = 0; j < 4; ++j)
                #pragma unroll
                for (int q = 0; q < 4; ++q) {
                    const int c = w * 64 + (ih * 2 + ii) * 16 + lg * 4 + q;
                    const size_t idx = (size_t)c * NPIX + n0 + j * 16 + li;
                    out[(size_t)b * CH * NPIX + idx] =
                        xb[idx] + nrm[j] * accP[ii][j][q] + gcv * acc[ii][j][q];
                }
    }
}

extern "C" void kernel_launch(void* const* d_in, const int* in_sizes, int n_in,
                              void* d_out, int out_size, void* d_ws, size_t ws_size,
                              hipStream_t stream)
{
    const float* x  = (const float*)d_in[0];
    const float* wq = (const float*)d_in[1];
    const float* bq = (const float*)d_in[2];
    const float* wk = (const float*)d_in[3];
    const float* bk = (const float*)d_in[4];
    const float* wv = (const float*)d_in[5];
    const float* bv = (const float*)d_in[6];
    const float* gk = (const float*)d_in[7];
    const float* gc = (const float*)d_in[8];
    float* out = (float*)d_out;
    char* wsb = (char*)d_ws;

    unsigned short* ATTB = (unsigned short*)(wsb);
    unsigned short* KVTB = (unsigned short*)(wsb + 1048576);
    float* KSUM = (float*)(wsb + 1179648);
    float* XKR  = (float*)(wsb + 1180672);
    unsigned short* WQH = (unsigned short*)(wsb + 1442816);
    unsigned short* WQL = (unsigned short*)(wsb + 1459200);
    unsigned short* WKH = (unsigned short*)(wsb + 1475584);
    unsigned short* WKL = (unsigned short*)(wsb + 1491968);

    float* xkpart = out;                 // d_out as scratch (overwritten by k_final)
    float* enpart = out + XKPART_SZ;

    hipMemsetAsync(KSUM, 0, 256 * sizeof(float), stream);

    k_prep<<<dim3(32), dim3(256), 0, stream>>>(wq, wk, WQH, WQL, WKH, WKL);
    k_kx<<<dim3(NPIX / 64, NB), dim3(256), 0, stream>>>(x, WKH, WKL, bk, xkpart, KSUM);
    k_gram<<<dim3(3, SPLIT, NB), dim3(256), 0, stream>>>(x, enpart);
    k_xkreduce<<<dim3(NB * MDIM), dim3(CH), 0, stream>>>(xkpart, XKR);
    k_kv<<<dim3(NB, 4), dim3(256), 0, stream>>>(wv, bv, XKR, KSUM, KVTB);
    k_softmax<<<dim3(NB * CH), dim3(CH), 0, stream>>>(enpart, ATTB);
    k_final<<<dim3(NPIX / 64, NB), dim3(256), 0, stream>>>(x, WQH, WQL, bq, KVTB, KSUM,
                                                           ATTB, gk, gc, out);
}

// Round 9
// 313.013 us; speedup vs baseline: 1.4736x; 1.4736x over previous
//
#include <hip/hip_runtime.h>
#include <math.h>

#define NPIX 16384
#define CH 256
#define MDIM 32
#define NB 8
#define EPSF 1e-6f
#define SPLIT 16
#define KCH (NPIX / SPLIT)   // 1024

// ws BYTE layout
//   ATTB @ 0        : bf16 attn·gc [B][C][D]  1,048,576 B
//   KVTB @ 1048576  : bf16 KV^T [B][C][M]       131,072 B
//   KSUM @ 1179648  : f32 [B][M]                  1,024 B
//   XKR  @ 1180672  : f32 [B][M][D]             262,144 B   (memset w/ KSUM)
//   WQH  @ 1442816  : bf16 [M][C] 16384 B
//   WQL  @ 1459200  : bf16 [M][C] 16384 B
//   WKH  @ 1475584  : bf16 [M][C] 16384 B
//   WKL  @ 1491968  : bf16 [M][C] 16384 B
// d_out doubles as scratch before k_final overwrites it (stream-ordered):
//   [0, 16777216) floats          xkpart [B][T=256][M][D=256]
//   [16777216, 25165824) floats   enpart [SPLIT=16][B][C][C]
#define XKPART_SZ 16777216ull

typedef short short8 __attribute__((ext_vector_type(8)));
typedef float f32x4 __attribute__((ext_vector_type(4)));

__device__ inline unsigned short f2bf(float v) {
    unsigned u = __builtin_bit_cast(unsigned, v);
    unsigned r = u + 0x7FFFu + ((u >> 16) & 1u);   // RNE (finite inputs)
    return (unsigned short)(r >> 16);
}
__device__ inline float bf2f(unsigned short h) {
    unsigned u = (unsigned)h << 16;
    return __builtin_bit_cast(float, u);
}

// Pre-split wq/wk into hi/lo bf16 pairs.
__global__ void k_prep(const float* __restrict__ wq, const float* __restrict__ wk,
                       unsigned short* __restrict__ WQH, unsigned short* __restrict__ WQL,
                       unsigned short* __restrict__ WKH, unsigned short* __restrict__ WKL)
{
    int i = blockIdx.x * 256 + threadIdx.x;   // 8192 total
    float q = wq[i], k = wk[i];
    unsigned short qh = f2bf(q);
    WQH[i] = qh; WQL[i] = f2bf(q - bf2f(qh));
    unsigned short kh = f2bf(k);
    WKH[i] = kh; WKL[i] = f2bf(k - bf2f(kh));
}

// Single-staging k_kx (unchanged from round 7).
__global__ __launch_bounds__(256, 4) void k_kx(
    const float* __restrict__ x,
    const unsigned short* __restrict__ WKH, const unsigned short* __restrict__ WKL,
    const float* __restrict__ bk,
    float* __restrict__ xkpart, float* __restrict__ Ksum)
{
    __shared__ unsigned short xs[CH * 72];     // 36 KB bf16 x tile [d][64n + hash pad]
    __shared__ unsigned short ksm[MDIM * 72];  // 4.5 KB bf16 softplus(K) [m][n]
    const int b = blockIdx.y, t = blockIdx.x, n0 = t * 64, tid = threadIdx.x;
    const int w = tid >> 6, l = tid & 63;
    const int li = l & 15, lg = l >> 4;
    const float* xb = x + (size_t)b * CH * NPIX;

    #pragma unroll
    for (int s = 0; s < 8; ++s) {
        int e8 = tid + s * 256;
        int c = e8 >> 3, j8 = e8 & 7;
        const float* src = xb + (size_t)c * NPIX + n0 + j8 * 8;
        float4 v0 = *(const float4*)src;
        float4 v1 = *(const float4*)(src + 4);
        float vv[8] = {v0.x, v0.y, v0.z, v0.w, v1.x, v1.y, v1.z, v1.w};
        short8 p;
        #pragma unroll
        for (int e = 0; e < 8; ++e) p[e] = (short)f2bf(vv[e]);
        const int g = j8 ^ (c & 7) ^ ((c >> 3) & 7);
        *(short8*)&xs[c * 72 + g * 8] = p;
    }
    __syncthreads();

    {   // K via MFMA; wave w covers n = w*16 + li
        f32x4 accq[2];
        accq[0] = (f32x4){0.f, 0.f, 0.f, 0.f};
        accq[1] = (f32x4){0.f, 0.f, 0.f, 0.f};
        const int n = w * 16 + li;
        const int gn = n >> 3, inn = n & 7;
        #pragma unroll
        for (int kc = 0; kc < 8; ++kc) {
            short8 bxw;
            #pragma unroll
            for (int e = 0; e < 8; ++e) {
                const int d = kc * 32 + lg * 8 + e;
                const int g = gn ^ e ^ ((kc * 4 + lg) & 7);
                bxw[e] = (short)xs[d * 72 + g * 8 + inn];
            }
            #pragma unroll
            for (int i = 0; i < 2; ++i) {
                short8 wh = *(const short8*)(WKH + (size_t)(i * 16 + li) * CH + kc * 32 + lg * 8);
                short8 wl = *(const short8*)(WKL + (size_t)(i * 16 + li) * CH + kc * 32 + lg * 8);
                accq[i] = __builtin_amdgcn_mfma_f32_16x16x32_bf16(wh, bxw, accq[i], 0, 0, 0);
                accq[i] = __builtin_amdgcn_mfma_f32_16x16x32_bf16(wl, bxw, accq[i], 0, 0, 0);
            }
        }
        #pragma unroll
        for (int i = 0; i < 2; ++i)
            #pragma unroll
            for (int q = 0; q < 4; ++q) {
                const int m = i * 16 + lg * 4 + q;
                float kv = accq[i][q] + bk[m];
                kv = fmaxf(kv, 0.f) + log1pf(expf(-fabsf(kv)));  // softplus
                ksm[m * 72 + (n ^ ((m & 7) << 3))] = f2bf(kv);
            }
    }
    __syncthreads();

    if (tid < MDIM) {
        float s = 0.f;
        #pragma unroll
        for (int j = 0; j < 64; ++j)
            s += bf2f(ksm[tid * 72 + (j ^ ((tid & 7) << 3))]);
        atomicAdd(&Ksum[b * MDIM + tid], s);
    }

    f32x4 axk[4][2];
    #pragma unroll
    for (int i = 0; i < 4; ++i)
        #pragma unroll
        for (int j = 0; j < 2; ++j) axk[i][j] = (f32x4){0.f, 0.f, 0.f, 0.f};

    #pragma unroll
    for (int ks2 = 0; ks2 < 2; ++ks2) {
        const int nc = ks2 * 32 + lg * 8;
        short8 kfr[2];
        #pragma unroll
        for (int j = 0; j < 2; ++j) {
            const int m = j * 16 + li;
            kfr[j] = *(const short8*)&ksm[m * 72 + (nc ^ ((m & 7) << 3))];
        }
        #pragma unroll
        for (int i = 0; i < 4; ++i) {
            const int d = w * 64 + i * 16 + li;
            const int g = (nc >> 3) ^ (d & 7) ^ ((d >> 3) & 7);
            short8 xf = *(const short8*)&xs[d * 72 + g * 8];
            #pragma unroll
            for (int j = 0; j < 2; ++j)
                axk[i][j] = __builtin_amdgcn_mfma_f32_16x16x32_bf16(kfr[j], xf, axk[i][j], 0, 0, 0);
        }
    }

    __syncthreads();
    float* xsF = (float*)xs;
    #pragma unroll
    for (int i = 0; i < 4; ++i)
        #pragma unroll
        for (int j = 0; j < 2; ++j)
            #pragma unroll
            for (int q = 0; q < 4; ++q) {
                const int m = j * 16 + lg * 4 + q;
                const int d = w * 64 + i * 16 + li;
                xsF[m * 256 + (d ^ ((m & 7) << 2))] = axk[i][j][q];
            }
    __syncthreads();
    float* xp = xkpart + (size_t)(b * 256 + t) * MDIM * CH;
    #pragma unroll 4
    for (int m = 0; m < MDIM; ++m)
        xp[m * CH + tid] = xsF[m * 256 + (tid ^ ((m & 7) << 2))];
}

// 4-way t-split reduction (was 1 block per (b,m): serial latency-bound).
__global__ void k_xkreduce(const float* __restrict__ xkpart, float* __restrict__ XKR) {
    const int b = blockIdx.x >> 5, m = blockIdx.x & 31, d = threadIdx.x;
    const int t0 = blockIdx.y * 64;
    float s = 0.f;
    #pragma unroll 4
    for (int t = t0; t < t0 + 64; ++t)
        s += xkpart[(((size_t)b * 256 + t) * MDIM + m) * CH + d];
    atomicAdd(&XKR[((size_t)b * MDIM + m) * CH + d], s);
}

// KV^T[c][m] (bf16) = sum_d wv[c][d]*XKR[m][d] + bv[c]*Ksum[m]
__global__ void k_kv(const float* __restrict__ wv, const float* __restrict__ bv,
                     const float* __restrict__ XKR, const float* __restrict__ Ksum,
                     unsigned short* __restrict__ KVTb) {
    const int b = blockIdx.x, q = blockIdx.y;
    const int ci = threadIdx.x & 63, mg = threadIdx.x >> 6;
    const int c = q * 64 + ci;
    float s[8];
    const float bvc = bv[c];
    #pragma unroll
    for (int i = 0; i < 8; ++i) s[i] = bvc * Ksum[b * MDIM + mg * 8 + i];
    #pragma unroll 4
    for (int d = 0; d < CH; ++d) {
        float w = wv[(size_t)c * CH + d];
        #pragma unroll
        for (int i = 0; i < 8; ++i)
            s[i] = fmaf(w, XKR[((size_t)b * MDIM + mg * 8 + i) * CH + d], s[i]);
    }
    short8 p;
    #pragma unroll
    for (int i = 0; i < 8; ++i) p[i] = (short)f2bf(s[i]);
    *(short8*)(KVTb + ((size_t)b * CH + c) * MDIM + mg * 8) = p;
}

// Gram via split-bf16 MFMA, symmetry-aware (SPLIT=16).
__global__ __launch_bounds__(256, 2) void k_gram(const float* __restrict__ x,
                                                 float* __restrict__ enpart)
{
    __shared__ unsigned short lds[4 * 128 * 72];
    unsigned short* Ah = lds;
    unsigned short* Al = lds + 128 * 72;
    unsigned short* Bh = lds + 2 * 128 * 72;
    unsigned short* Bl = lds + 3 * 128 * 72;

    const int tid = threadIdx.x;
    const int rt = (blockIdx.x == 2) ? 1 : 0;
    const int ct = (blockIdx.x == 0) ? 0 : 1;
    const bool diag = (rt == ct);
    const int sp = blockIdx.y, b = blockIdx.z;
    const int r0 = rt * 128, c0 = ct * 128;
    const float* xb = x + (size_t)b * CH * NPIX;
    const int k0base = sp * KCH;

    unsigned short* Bh_p = diag ? Ah : Bh;
    unsigned short* Bl_p = diag ? Al : Bl;

    const int wave = tid >> 6, lane = tid & 63;
    const int wr = wave >> 1, wc = wave & 1;

    f32x4 acc[4][4];
    #pragma unroll
    for (int i = 0; i < 4; ++i)
        #pragma unroll
        for (int j = 0; j < 4; ++j)
            acc[i][j] = (f32x4){0.f, 0.f, 0.f, 0.f};

    const int oct = tid & 7;
    const int frow = tid >> 3;

    for (int kk = 0; kk < KCH; kk += 64) {
        __syncthreads();
        const int k0 = k0base + kk;
        #pragma unroll
        for (int half = 0; half < 2; ++half) {
            if (half && diag) continue;
            const int rowbase = half ? c0 : r0;
            unsigned short* Hh = half ? Bh : Ah;
            unsigned short* Hl = half ? Bl : Al;
            #pragma unroll
            for (int s = 0; s < 4; ++s) {
                const int r = frow + s * 32;
                const float* src = xb + (size_t)(rowbase + r) * NPIX + k0 + oct * 8;
                float4 v0 = *(const float4*)src;
                float4 v1 = *(const float4*)(src + 4);
                float vv[8] = {v0.x, v0.y, v0.z, v0.w, v1.x, v1.y, v1.z, v1.w};
                short8 ph, pl;
                #pragma unroll
                for (int e = 0; e < 8; ++e) {
                    unsigned short h = f2bf(vv[e]);
                    unsigned short l = f2bf(vv[e] - bf2f(h));
                    ph[e] = (short)h;
                    pl[e] = (short)l;
                }
                *(short8*)&Hh[r * 72 + oct * 8] = ph;
                *(short8*)&Hl[r * 72 + oct * 8] = pl;
            }
        }
        __syncthreads();

        #pragma unroll
        for (int ks2 = 0; ks2 < 2; ++ks2) {
            short8 ah[4], al[4], bh[4], bl[4];
            const int rbase = wr * 64 + (lane & 15);
            const int cbase = wc * 64 + (lane & 15);
            const int koff = ks2 * 32 + (lane >> 4) * 8;
            #pragma unroll
            for (int f = 0; f < 4; ++f) {
                ah[f] = *(const short8*)&Ah[(rbase + f * 16) * 72 + koff];
                al[f] = *(const short8*)&Al[(rbase + f * 16) * 72 + koff];
                bh[f] = *(const short8*)&Bh_p[(cbase + f * 16) * 72 + koff];
                bl[f] = *(const short8*)&Bl_p[(cbase + f * 16) * 72 + koff];
            }
            #pragma unroll
            for (int i = 0; i < 4; ++i)
                #pragma unroll
                for (int j = 0; j < 4; ++j) {
                    acc[i][j] = __builtin_amdgcn_mfma_f32_16x16x32_bf16(ah[i], bh[j], acc[i][j], 0, 0, 0);
                    acc[i][j] = __builtin_amdgcn_mfma_f32_16x16x32_bf16(ah[i], bl[j], acc[i][j], 0, 0, 0);
                    acc[i][j] = __builtin_amdgcn_mfma_f32_16x16x32_bf16(al[i], bh[j], acc[i][j], 0, 0, 0);
                }
        }
    }

    float* ep = enpart + (size_t)(sp * NB + b) * (CH * CH);
    const int rw = (lane >> 4) * 4;
    const int cw = lane & 15;
    #pragma unroll
    for (int i = 0; i < 4; ++i)
        #pragma unroll
        for (int j = 0; j < 4; ++j) {
            const int row = r0 + wr * 64 + i * 16 + rw;
            const int col = c0 + wc * 64 + j * 16 + cw;
            #pragma unroll
            for (int q = 0; q < 4; ++q) {
                float v = acc[i][j][q];
                ep[(size_t)(row + q) * CH + col] = v;
                if (!diag) ep[(size_t)col * CH + (row + q)] = v;
            }
        }
}

// softmin over summed partials; emits bf16 (gc * attn) [b][c][d] — gc folded
// here so k_final can accumulate KAM+CAM in ONE accumulator set.
__global__ void k_softmax(const float* __restrict__ enpart,
                          const float* __restrict__ gc,
                          unsigned short* __restrict__ attnb) {
    const int b = blockIdx.x >> 8, c = blockIdx.x & 255;
    const int d = threadIdx.x;
    __shared__ float red[8];
    float e = 0.f;
    #pragma unroll
    for (int sp = 0; sp < SPLIT; ++sp)
        e += enpart[(size_t)(sp * NB + b) * (CH * CH) + (size_t)c * CH + d];
    float mn = e;
    #pragma unroll
    for (int o = 1; o < 64; o <<= 1) mn = fminf(mn, __shfl_xor(mn, o));
    if ((d & 63) == 0) red[d >> 6] = mn;
    __syncthreads();
    mn = fminf(fminf(red[0], red[1]), fminf(red[2], red[3]));
    float w = expf(mn - e);
    float s = w;
    #pragma unroll
    for (int o = 1; o < 64; o <<= 1) s += __shfl_xor(s, o);
    if ((d & 63) == 0) red[4 + (d >> 6)] = s;
    __syncthreads();
    s = red[4] + red[5] + red[6] + red[7];
    attnb[((size_t)(b * CH) + c) * CH + d] = f2bf(gc[0] * w / s);
}

// out = x + (nrm·Q)^T·KV + (gc·attn)·X — both scalars folded into operands so
// KAM and CAM share ONE accumulator (64 regs, was 128).  Single-pass epilogue
// (round-8 two-pass split broke L2 write-merging: WRITE 131->360 MB).
__global__ __launch_bounds__(256, 3) void k_final(
    const float* __restrict__ x,
    const unsigned short* __restrict__ WQH, const unsigned short* __restrict__ WQL,
    const float* __restrict__ bq,
    const unsigned short* __restrict__ KVTb, const float* __restrict__ Ksum,
    const unsigned short* __restrict__ attnb, const float* __restrict__ gk,
    float* __restrict__ out)
{
    __shared__ uint2 xsTv[4096];            // 32 KB: bf16 xT [n=64][d=256] swizzled
    __shared__ unsigned short qsT[64 * 40]; // 5 KB: bf16 (nrm·Q) [n][m] (pad 40)
    unsigned char* xsT = (unsigned char*)xsTv;
    const int b = blockIdx.y, n0 = blockIdx.x * 64, tid = threadIdx.x;
    const int w = tid >> 6, l = tid & 63;
    const int li = l & 15, lg = l >> 4;
    const float* xb = x + (size_t)b * CH * NPIX;

    // ---- stage xT ----
    {
        const int n4 = li * 4;
        const bool o1 = lg & 1, o2 = (lg >> 1) & 1;
        #pragma unroll
        for (int p = 0; p < 16; ++p) {
            const int d0 = w * 64 + p * 4;
            float4 vv = *(const float4*)(xb + (size_t)(d0 + lg) * NPIX + n0 + n4);
            float v0 = vv.x, v1 = vv.y, v2 = vv.z, v3 = vv.w;
            float r1 = __shfl_xor(o1 ? v0 : v1, 16);
            float r2 = __shfl_xor(o1 ? v2 : v3, 16);
            float a0 = o1 ? r1 : v0, a1 = o1 ? v1 : r1;
            float a2 = o1 ? r2 : v2, a3 = o1 ? v3 : r2;
            float r3 = __shfl_xor(o2 ? a0 : a2, 32);
            float r4 = __shfl_xor(o2 ? a1 : a3, 32);
            float b0 = o2 ? r3 : a0, b1 = o2 ? r4 : a1;
            float b2 = o2 ? a2 : r3, b3 = o2 ? a3 : r4;
            const int nl = n4 + lg;
            unsigned lo = (unsigned)f2bf(b0) | ((unsigned)f2bf(b1) << 16);
            unsigned hi = (unsigned)f2bf(b2) | ((unsigned)f2bf(b3) << 16);
            const int off = nl * 512 +
                ((2 * d0) ^ ((nl & 7) << 4) ^ (((nl >> 3) & 1) << 3));
            *(uint2*)(xsT + off) = make_uint2(lo, hi);
        }
    }
    __syncthreads();

    // ---- inline Q via MFMA; write qsT PRE-SCALED by nrm = gk/den ----
    {
        f32x4 accq[2];
        accq[0] = (f32x4){0.f, 0.f, 0.f, 0.f};
        accq[1] = (f32x4){0.f, 0.f, 0.f, 0.f};
        const int nf = w * 16 + li;
        const int sw = ((nf & 7) << 4) ^ (((nf >> 3) & 1) << 3);
        #pragma unroll
        for (int kc = 0; kc < 8; ++kc) {
            const int d2 = 2 * (kc * 32 + lg * 8);
            uint2 h0 = *(const uint2*)(xsT + nf * 512 + (d2 ^ sw));
            uint2 h1 = *(const uint2*)(xsT + nf * 512 + ((d2 + 8) ^ sw));
            int4 tmp = make_int4(h0.x, h0.y, h1.x, h1.y);
            short8 bxw = __builtin_bit_cast(short8, tmp);
            #pragma unroll
            for (int i = 0; i < 2; ++i) {
                short8 wh = *(const short8*)(WQH + (size_t)(i * 16 + li) * CH + kc * 32 + lg * 8);
                short8 wl = *(const short8*)(WQL + (size_t)(i * 16 + li) * CH + kc * 32 + lg * 8);
                accq[i] = __builtin_amdgcn_mfma_f32_16x16x32_bf16(wh, bxw, accq[i], 0, 0, 0);
                accq[i] = __builtin_amdgcn_mfma_f32_16x16x32_bf16(wl, bxw, accq[i], 0, 0, 0);
            }
        }
        float qvv[8];
        float den = 0.f;
        #pragma unroll
        for (int i = 0; i < 2; ++i)
            #pragma unroll
            for (int q = 0; q < 4; ++q) {
                const int m = i * 16 + lg * 4 + q;
                float qv = accq[i][q] + bq[m];
                qv = fmaxf(qv, 0.f) + log1pf(expf(-fabsf(qv)));  // softplus
                qvv[i * 4 + q] = qv;
                den = fmaf(qv, Ksum[b * MDIM + m] + EPSF, den);
            }
        den += __shfl_xor(den, 16);
        den += __shfl_xor(den, 32);
        const float nrm = gk[0] / den;
        #pragma unroll
        for (int i = 0; i < 2; ++i)
            #pragma unroll
            for (int q = 0; q < 4; ++q) {
                const int m = i * 16 + lg * 4 + q;
                qsT[nf * 40 + m] = f2bf(qvv[i * 4 + q] * nrm);
            }
    }
    __syncthreads();

    f32x4 acc[4][4];
    #pragma unroll
    for (int i = 0; i < 4; ++i)
        #pragma unroll
        for (int j = 0; j < 4; ++j)
            acc[i][j] = (f32x4){0.f, 0.f, 0.f, 0.f};

    // ---- KAM: acc = KV^T · (nrm·Q) ----
    {
        short8 qb[4];
        #pragma unroll
        for (int j = 0; j < 4; ++j)
            qb[j] = *(const short8*)&qsT[(j * 16 + li) * 40 + lg * 8];
        #pragma unroll
        for (int i = 0; i < 4; ++i) {
            short8 ka = *(const short8*)(KVTb +
                ((size_t)b * CH + w * 64 + i * 16 + li) * MDIM + lg * 8);
            #pragma unroll
            for (int j = 0; j < 4; ++j)
                acc[i][j] = __builtin_amdgcn_mfma_f32_16x16x32_bf16(ka, qb[j], acc[i][j], 0, 0, 0);
        }
    }

    // ---- CAM: acc += (gc·attn) · X ----
    const unsigned short* ab = attnb + (size_t)b * CH * CH;
    for (int kk = 0; kk < CH; kk += 32) {
        short8 af[4], bx[4];
        #pragma unroll
        for (int i = 0; i < 4; ++i)
            af[i] = *(const short8*)(ab +
                (size_t)(w * 64 + i * 16 + li) * CH + kk + lg * 8);
        #pragma unroll
        for (int j = 0; j < 4; ++j) {
            const int nf = j * 16 + li;
            const int d2 = 2 * (kk + lg * 8);
            const int sw = ((nf & 7) << 4) ^ (((nf >> 3) & 1) << 3);
            uint2 h0 = *(const uint2*)(xsT + nf * 512 + (d2 ^ sw));
            uint2 h1 = *(const uint2*)(xsT + nf * 512 + ((d2 + 8) ^ sw));
            int4 tmp = make_int4(h0.x, h0.y, h1.x, h1.y);
            bx[j] = __builtin_bit_cast(short8, tmp);
        }
        #pragma unroll
        for (int i = 0; i < 4; ++i)
            #pragma unroll
            for (int j = 0; j < 4; ++j)
                acc[i][j] = __builtin_amdgcn_mfma_f32_16x16x32_bf16(af[i], bx[j], acc[i][j], 0, 0, 0);
    }

    // ---- epilogue: out = x + acc (single pass, same pattern as round 7) ----
    #pragma unroll
    for (int i = 0; i < 4; ++i)
        #pragma unroll
        for (int j = 0; j < 4; ++j)
            #pragma unroll
            for (int q = 0; q < 4; ++q) {
                const int c = w * 64 + i * 16 + lg * 4 + q;
                const size_t idx = (size_t)c * NPIX + n0 + j * 16 + li;
                out[(size_t)b * CH * NPIX + idx] = xb[idx] + acc[i][j][q];
            }
}

extern "C" void kernel_launch(void* const* d_in, const int* in_sizes, int n_in,
                              void* d_out, int out_size, void* d_ws, size_t ws_size,
                              hipStream_t stream)
{
    const float* x  = (const float*)d_in[0];
    const float* wq = (const float*)d_in[1];
    const float* bq = (const float*)d_in[2];
    const float* wk = (const float*)d_in[3];
    const float* bk = (const float*)d_in[4];
    const float* wv = (const float*)d_in[5];
    const float* bv = (const float*)d_in[6];
    const float* gk = (const float*)d_in[7];
    const float* gc = (const float*)d_in[8];
    float* out = (float*)d_out;
    char* wsb = (char*)d_ws;

    unsigned short* ATTB = (unsigned short*)(wsb);
    unsigned short* KVTB = (unsigned short*)(wsb + 1048576);
    float* KSUM = (float*)(wsb + 1179648);
    float* XKR  = (float*)(wsb + 1180672);
    unsigned short* WQH = (unsigned short*)(wsb + 1442816);
    unsigned short* WQL = (unsigned short*)(wsb + 1459200);
    unsigned short* WKH = (unsigned short*)(wsb + 1475584);
    unsigned short* WKL = (unsigned short*)(wsb + 1491968);

    float* xkpart = out;                 // d_out as scratch (overwritten by k_final)
    float* enpart = out + XKPART_SZ;

    // zero KSUM (1 KB) + XKR (256 KB) — contiguous
    hipMemsetAsync(KSUM, 0, 1024 + 262144, stream);

    k_prep<<<dim3(32), dim3(256), 0, stream>>>(wq, wk, WQH, WQL, WKH, WKL);
    k_kx<<<dim3(NPIX / 64, NB), dim3(256), 0, stream>>>(x, WKH, WKL, bk, xkpart, KSUM);
    k_gram<<<dim3(3, SPLIT, NB), dim3(256), 0, stream>>>(x, enpart);
    k_xkreduce<<<dim3(NB * MDIM, 4), dim3(CH), 0, stream>>>(xkpart, XKR);
    k_kv<<<dim3(NB, 4), dim3(256), 0, stream>>>(wv, bv, XKR, KSUM, KVTB);
    k_softmax<<<dim3(NB * CH), dim3(CH), 0, stream>>>(enpart, gc, ATTB);
    k_final<<<dim3(NPIX / 64, NB), dim3(256), 0, stream>>>(x, WQH, WQL, bq, KVTB, KSUM,
                                                           ATTB, gk, out);
}

// Round 10
// 303.688 us; speedup vs baseline: 1.5189x; 1.0307x over previous
//
#include <hip/hip_runtime.h>
#include <math.h>

#define NPIX 16384
#define CH 256
#define MDIM 32
#define NB 8
#define EPSF 1e-6f
#define SPLIT 16
#define KCH (NPIX / SPLIT)   // 1024

// ws BYTE layout
//   ATTB @ 0        : bf16 attn·gc [B][C][D]  1,048,576 B
//   KVTB @ 1048576  : bf16 KV^T [B][C][M]       131,072 B
//   KSUM @ 1179648  : f32 [B][M]                  1,024 B
//   XKR  @ 1180672  : f32 [B][M][D]             262,144 B   (memset w/ KSUM)
//   WQH  @ 1442816  : bf16 [M][C] 16384 B
//   WQL  @ 1459200  : bf16 [M][C] 16384 B
//   WKH  @ 1475584  : bf16 [M][C] 16384 B
//   WKL  @ 1491968  : bf16 [M][C] 16384 B
// d_out doubles as scratch before k_final overwrites it (stream-ordered):
//   [0, 33554432) bytes           xkpart bf16 [B][T=256][M][D=256]
//   [67108864, 100663296) bytes   enpart f32 [SPLIT=16][B][C][C]
#define XKPART_F32OFF 16777216ull   // float offset of enpart in d_out

typedef short short4v __attribute__((ext_vector_type(4)));
typedef short short8 __attribute__((ext_vector_type(8)));
typedef float f32x4 __attribute__((ext_vector_type(4)));

__device__ inline unsigned short f2bf(float v) {
    unsigned u = __builtin_bit_cast(unsigned, v);
    unsigned r = u + 0x7FFFu + ((u >> 16) & 1u);   // RNE (finite inputs)
    return (unsigned short)(r >> 16);
}
__device__ inline float bf2f(unsigned short h) {
    unsigned u = (unsigned)h << 16;
    return __builtin_bit_cast(float, u);
}

// Pre-split wq/wk into hi/lo bf16 pairs.
__global__ void k_prep(const float* __restrict__ wq, const float* __restrict__ wk,
                       unsigned short* __restrict__ WQH, unsigned short* __restrict__ WQL,
                       unsigned short* __restrict__ WKH, unsigned short* __restrict__ WKL)
{
    int i = blockIdx.x * 256 + threadIdx.x;   // 8192 total
    float q = wq[i], k = wk[i];
    unsigned short qh = f2bf(q);
    WQH[i] = qh; WQL[i] = f2bf(q - bf2f(qh));
    unsigned short kh = f2bf(k);
    WKH[i] = kh; WKL[i] = f2bf(k - bf2f(kh));
}

// k_kx: phase-3 MFMA operands SWAPPED (rows=d) -> lanes hold 4 consecutive d;
// partials stored bf16 straight to global (no LDS transpose round-trip).
__global__ __launch_bounds__(256, 4) void k_kx(
    const float* __restrict__ x,
    const unsigned short* __restrict__ WKH, const unsigned short* __restrict__ WKL,
    const float* __restrict__ bk,
    unsigned short* __restrict__ xkpart, float* __restrict__ Ksum)
{
    __shared__ unsigned short xs[CH * 72];     // 36 KB bf16 x tile [d][64n + hash pad]
    __shared__ unsigned short ksm[MDIM * 72];  // 4.5 KB bf16 softplus(K) [m][n]
    const int b = blockIdx.y, t = blockIdx.x, n0 = t * 64, tid = threadIdx.x;
    const int w = tid >> 6, l = tid & 63;
    const int li = l & 15, lg = l >> 4;
    const float* xb = x + (size_t)b * CH * NPIX;

    #pragma unroll
    for (int s = 0; s < 8; ++s) {
        int e8 = tid + s * 256;
        int c = e8 >> 3, j8 = e8 & 7;
        const float* src = xb + (size_t)c * NPIX + n0 + j8 * 8;
        float4 v0 = *(const float4*)src;
        float4 v1 = *(const float4*)(src + 4);
        float vv[8] = {v0.x, v0.y, v0.z, v0.w, v1.x, v1.y, v1.z, v1.w};
        short8 p;
        #pragma unroll
        for (int e = 0; e < 8; ++e) p[e] = (short)f2bf(vv[e]);
        const int g = j8 ^ (c & 7) ^ ((c >> 3) & 7);
        *(short8*)&xs[c * 72 + g * 8] = p;
    }
    __syncthreads();

    {   // K via MFMA; wave w covers n = w*16 + li
        f32x4 accq[2];
        accq[0] = (f32x4){0.f, 0.f, 0.f, 0.f};
        accq[1] = (f32x4){0.f, 0.f, 0.f, 0.f};
        const int n = w * 16 + li;
        const int gn = n >> 3, inn = n & 7;
        #pragma unroll
        for (int kc = 0; kc < 8; ++kc) {
            short8 bxw;
            #pragma unroll
            for (int e = 0; e < 8; ++e) {
                const int d = kc * 32 + lg * 8 + e;
                const int g = gn ^ e ^ ((kc * 4 + lg) & 7);
                bxw[e] = (short)xs[d * 72 + g * 8 + inn];
            }
            #pragma unroll
            for (int i = 0; i < 2; ++i) {
                short8 wh = *(const short8*)(WKH + (size_t)(i * 16 + li) * CH + kc * 32 + lg * 8);
                short8 wl = *(const short8*)(WKL + (size_t)(i * 16 + li) * CH + kc * 32 + lg * 8);
                accq[i] = __builtin_amdgcn_mfma_f32_16x16x32_bf16(wh, bxw, accq[i], 0, 0, 0);
                accq[i] = __builtin_amdgcn_mfma_f32_16x16x32_bf16(wl, bxw, accq[i], 0, 0, 0);
            }
        }
        #pragma unroll
        for (int i = 0; i < 2; ++i)
            #pragma unroll
            for (int q = 0; q < 4; ++q) {
                const int m = i * 16 + lg * 4 + q;
                float kv = accq[i][q] + bk[m];
                kv = fmaxf(kv, 0.f) + log1pf(expf(-fabsf(kv)));  // softplus
                ksm[m * 72 + (n ^ ((m & 7) << 3))] = f2bf(kv);
            }
    }
    __syncthreads();

    if (tid < MDIM) {
        float s = 0.f;
        #pragma unroll
        for (int j = 0; j < 64; ++j)
            s += bf2f(ksm[tid * 72 + (j ^ ((tid & 7) << 3))]);
        atomicAdd(&Ksum[b * MDIM + tid], s);
    }

    // phase 3: XK partial via mfma(xf, kfr) -> D rows = d, cols = m.
    f32x4 axk[4][2];
    #pragma unroll
    for (int i = 0; i < 4; ++i)
        #pragma unroll
        for (int j = 0; j < 2; ++j) axk[i][j] = (f32x4){0.f, 0.f, 0.f, 0.f};

    #pragma unroll
    for (int ks2 = 0; ks2 < 2; ++ks2) {
        const int nc = ks2 * 32 + lg * 8;
        short8 kfr[2];
        #pragma unroll
        for (int j = 0; j < 2; ++j) {
            const int m = j * 16 + li;
            kfr[j] = *(const short8*)&ksm[m * 72 + (nc ^ ((m & 7) << 3))];
        }
        #pragma unroll
        for (int i = 0; i < 4; ++i) {
            const int d = w * 64 + i * 16 + li;
            const int g = (nc >> 3) ^ (d & 7) ^ ((d >> 3) & 7);
            short8 xf = *(const short8*)&xs[d * 72 + g * 8];
            #pragma unroll
            for (int j = 0; j < 2; ++j)
                axk[i][j] = __builtin_amdgcn_mfma_f32_16x16x32_bf16(xf, kfr[j], axk[i][j], 0, 0, 0);
        }
    }

    // direct bf16 stores: lane holds m = j*16+li, d = w*64+i*16+lg*4 .. +3
    unsigned short* xkp = xkpart + (size_t)(b * 256 + t) * MDIM * CH;
    #pragma unroll
    for (int i = 0; i < 4; ++i)
        #pragma unroll
        for (int j = 0; j < 2; ++j) {
            short4v pk;
            #pragma unroll
            for (int q = 0; q < 4; ++q) pk[q] = (short)f2bf(axk[i][j][q]);
            *(short4v*)(xkp + (size_t)(j * 16 + li) * CH + w * 64 + i * 16 + lg * 4) = pk;
        }
}

// 4-way t-split reduction over bf16 partials.
__global__ void k_xkreduce(const unsigned short* __restrict__ xkpart,
                           float* __restrict__ XKR) {
    const int b = blockIdx.x >> 5, m = blockIdx.x & 31, d = threadIdx.x;
    const int t0 = blockIdx.y * 64;
    float s = 0.f;
    #pragma unroll 4
    for (int t = t0; t < t0 + 64; ++t)
        s += bf2f(xkpart[(((size_t)b * 256 + t) * MDIM + m) * CH + d]);
    atomicAdd(&XKR[((size_t)b * MDIM + m) * CH + d], s);
}

// KV^T[c][m] (bf16) = sum_d wv[c][d]*XKR[m][d] + bv[c]*Ksum[m]
__global__ void k_kv(const float* __restrict__ wv, const float* __restrict__ bv,
                     const float* __restrict__ XKR, const float* __restrict__ Ksum,
                     unsigned short* __restrict__ KVTb) {
    const int b = blockIdx.x, q = blockIdx.y;
    const int ci = threadIdx.x & 63, mg = threadIdx.x >> 6;
    const int c = q * 64 + ci;
    float s[8];
    const float bvc = bv[c];
    #pragma unroll
    for (int i = 0; i < 8; ++i) s[i] = bvc * Ksum[b * MDIM + mg * 8 + i];
    #pragma unroll 4
    for (int d = 0; d < CH; ++d) {
        float w = wv[(size_t)c * CH + d];
        #pragma unroll
        for (int i = 0; i < 8; ++i)
            s[i] = fmaf(w, XKR[((size_t)b * MDIM + mg * 8 + i) * CH + d], s[i]);
    }
    short8 p;
    #pragma unroll
    for (int i = 0; i < 8; ++i) p[i] = (short)f2bf(s[i]);
    *(short8*)(KVTb + ((size_t)b * CH + c) * MDIM + mg * 8) = p;
}

// Gram via split-bf16 MFMA, symmetry-aware (SPLIT=16) — unchanged.
__global__ __launch_bounds__(256, 2) void k_gram(const float* __restrict__ x,
                                                 float* __restrict__ enpart)
{
    __shared__ unsigned short lds[4 * 128 * 72];
    unsigned short* Ah = lds;
    unsigned short* Al = lds + 128 * 72;
    unsigned short* Bh = lds + 2 * 128 * 72;
    unsigned short* Bl = lds + 3 * 128 * 72;

    const int tid = threadIdx.x;
    const int rt = (blockIdx.x == 2) ? 1 : 0;
    const int ct = (blockIdx.x == 0) ? 0 : 1;
    const bool diag = (rt == ct);
    const int sp = blockIdx.y, b = blockIdx.z;
    const int r0 = rt * 128, c0 = ct * 128;
    const float* xb = x + (size_t)b * CH * NPIX;
    const int k0base = sp * KCH;

    unsigned short* Bh_p = diag ? Ah : Bh;
    unsigned short* Bl_p = diag ? Al : Bl;

    const int wave = tid >> 6, lane = tid & 63;
    const int wr = wave >> 1, wc = wave & 1;

    f32x4 acc[4][4];
    #pragma unroll
    for (int i = 0; i < 4; ++i)
        #pragma unroll
        for (int j = 0; j < 4; ++j)
            acc[i][j] = (f32x4){0.f, 0.f, 0.f, 0.f};

    const int oct = tid & 7;
    const int frow = tid >> 3;

    for (int kk = 0; kk < KCH; kk += 64) {
        __syncthreads();
        const int k0 = k0base + kk;
        #pragma unroll
        for (int half = 0; half < 2; ++half) {
            if (half && diag) continue;
            const int rowbase = half ? c0 : r0;
            unsigned short* Hh = half ? Bh : Ah;
            unsigned short* Hl = half ? Bl : Al;
            #pragma unroll
            for (int s = 0; s < 4; ++s) {
                const int r = frow + s * 32;
                const float* src = xb + (size_t)(rowbase + r) * NPIX + k0 + oct * 8;
                float4 v0 = *(const float4*)src;
                float4 v1 = *(const float4*)(src + 4);
                float vv[8] = {v0.x, v0.y, v0.z, v0.w, v1.x, v1.y, v1.z, v1.w};
                short8 ph, pl;
                #pragma unroll
                for (int e = 0; e < 8; ++e) {
                    unsigned short h = f2bf(vv[e]);
                    unsigned short l = f2bf(vv[e] - bf2f(h));
                    ph[e] = (short)h;
                    pl[e] = (short)l;
                }
                *(short8*)&Hh[r * 72 + oct * 8] = ph;
                *(short8*)&Hl[r * 72 + oct * 8] = pl;
            }
        }
        __syncthreads();

        #pragma unroll
        for (int ks2 = 0; ks2 < 2; ++ks2) {
            short8 ah[4], al[4], bh[4], bl[4];
            const int rbase = wr * 64 + (lane & 15);
            const int cbase = wc * 64 + (lane & 15);
            const int koff = ks2 * 32 + (lane >> 4) * 8;
            #pragma unroll
            for (int f = 0; f < 4; ++f) {
                ah[f] = *(const short8*)&Ah[(rbase + f * 16) * 72 + koff];
                al[f] = *(const short8*)&Al[(rbase + f * 16) * 72 + koff];
                bh[f] = *(const short8*)&Bh_p[(cbase + f * 16) * 72 + koff];
                bl[f] = *(const short8*)&Bl_p[(cbase + f * 16) * 72 + koff];
            }
            #pragma unroll
            for (int i = 0; i < 4; ++i)
                #pragma unroll
                for (int j = 0; j < 4; ++j) {
                    acc[i][j] = __builtin_amdgcn_mfma_f32_16x16x32_bf16(ah[i], bh[j], acc[i][j], 0, 0, 0);
                    acc[i][j] = __builtin_amdgcn_mfma_f32_16x16x32_bf16(ah[i], bl[j], acc[i][j], 0, 0, 0);
                    acc[i][j] = __builtin_amdgcn_mfma_f32_16x16x32_bf16(al[i], bh[j], acc[i][j], 0, 0, 0);
                }
        }
    }

    float* ep = enpart + (size_t)(sp * NB + b) * (CH * CH);
    const int rw = (lane >> 4) * 4;
    const int cw = lane & 15;
    #pragma unroll
    for (int i = 0; i < 4; ++i)
        #pragma unroll
        for (int j = 0; j < 4; ++j) {
            const int row = r0 + wr * 64 + i * 16 + rw;
            const int col = c0 + wc * 64 + j * 16 + cw;
            #pragma unroll
            for (int q = 0; q < 4; ++q) {
                float v = acc[i][j][q];
                ep[(size_t)(row + q) * CH + col] = v;
                if (!diag) ep[(size_t)col * CH + (row + q)] = v;
            }
        }
}

// softmin over summed partials; emits bf16 (gc * attn) [b][c][d].
__global__ void k_softmax(const float* __restrict__ enpart,
                          const float* __restrict__ gc,
                          unsigned short* __restrict__ attnb) {
    const int b = blockIdx.x >> 8, c = blockIdx.x & 255;
    const int d = threadIdx.x;
    __shared__ float red[8];
    float e = 0.f;
    #pragma unroll
    for (int sp = 0; sp < SPLIT; ++sp)
        e += enpart[(size_t)(sp * NB + b) * (CH * CH) + (size_t)c * CH + d];
    float mn = e;
    #pragma unroll
    for (int o = 1; o < 64; o <<= 1) mn = fminf(mn, __shfl_xor(mn, o));
    if ((d & 63) == 0) red[d >> 6] = mn;
    __syncthreads();
    mn = fminf(fminf(red[0], red[1]), fminf(red[2], red[3]));
    float w = expf(mn - e);
    float s = w;
    #pragma unroll
    for (int o = 1; o < 64; o <<= 1) s += __shfl_xor(s, o);
    if ((d & 63) == 0) red[4 + (d >> 6)] = s;
    __syncthreads();
    s = red[4] + red[5] + red[6] + red[7];
    attnb[((size_t)(b * CH) + c) * CH + d] = f2bf(gc[0] * w / s);
}

// out = x + (nrm·Q)^T·KV + (gc·attn)·X.  MFMA operands SWAPPED so acc rows = n:
// epilogue is float4 loads/stores (was 64+64 scalar dwords per thread).
__global__ __launch_bounds__(256, 3) void k_final(
    const float* __restrict__ x,
    const unsigned short* __restrict__ WQH, const unsigned short* __restrict__ WQL,
    const float* __restrict__ bq,
    const unsigned short* __restrict__ KVTb, const float* __restrict__ Ksum,
    const unsigned short* __restrict__ attnb, const float* __restrict__ gk,
    float* __restrict__ out)
{
    __shared__ uint2 xsTv[4096];            // 32 KB: bf16 xT [n=64][d=256] swizzled
    __shared__ unsigned short qsT[64 * 40]; // 5 KB: bf16 (nrm·Q) [n][m] (pad 40)
    unsigned char* xsT = (unsigned char*)xsTv;
    const int b = blockIdx.y, n0 = blockIdx.x * 64, tid = threadIdx.x;
    const int w = tid >> 6, l = tid & 63;
    const int li = l & 15, lg = l >> 4;
    const float* xb = x + (size_t)b * CH * NPIX;

    // ---- stage xT ----
    {
        const int n4 = li * 4;
        const bool o1 = lg & 1, o2 = (lg >> 1) & 1;
        #pragma unroll
        for (int p = 0; p < 16; ++p) {
            const int d0 = w * 64 + p * 4;
            float4 vv = *(const float4*)(xb + (size_t)(d0 + lg) * NPIX + n0 + n4);
            float v0 = vv.x, v1 = vv.y, v2 = vv.z, v3 = vv.w;
            float r1 = __shfl_xor(o1 ? v0 : v1, 16);
            float r2 = __shfl_xor(o1 ? v2 : v3, 16);
            float a0 = o1 ? r1 : v0, a1 = o1 ? v1 : r1;
            float a2 = o1 ? r2 : v2, a3 = o1 ? v3 : r2;
            float r3 = __shfl_xor(o2 ? a0 : a2, 32);
            float r4 = __shfl_xor(o2 ? a1 : a3, 32);
            float b0 = o2 ? r3 : a0, b1 = o2 ? r4 : a1;
            float b2 = o2 ? a2 : r3, b3 = o2 ? a3 : r4;
            const int nl = n4 + lg;
            unsigned lo = (unsigned)f2bf(b0) | ((unsigned)f2bf(b1) << 16);
            unsigned hi = (unsigned)f2bf(b2) | ((unsigned)f2bf(b3) << 16);
            const int off = nl * 512 +
                ((2 * d0) ^ ((nl & 7) << 4) ^ (((nl >> 3) & 1) << 3));
            *(uint2*)(xsT + off) = make_uint2(lo, hi);
        }
    }
    __syncthreads();

    // ---- inline Q via MFMA; write qsT PRE-SCALED by nrm = gk/den ----
    {
        f32x4 accq[2];
        accq[0] = (f32x4){0.f, 0.f, 0.f, 0.f};
        accq[1] = (f32x4){0.f, 0.f, 0.f, 0.f};
        const int nf = w * 16 + li;
        const int sw = ((nf & 7) << 4) ^ (((nf >> 3) & 1) << 3);
        #pragma unroll
        for (int kc = 0; kc < 8; ++kc) {
            const int d2 = 2 * (kc * 32 + lg * 8);
            uint2 h0 = *(const uint2*)(xsT + nf * 512 + (d2 ^ sw));
            uint2 h1 = *(const uint2*)(xsT + nf * 512 + ((d2 + 8) ^ sw));
            int4 tmp = make_int4(h0.x, h0.y, h1.x, h1.y);
            short8 bxw = __builtin_bit_cast(short8, tmp);
            #pragma unroll
            for (int i = 0; i < 2; ++i) {
                short8 wh = *(const short8*)(WQH + (size_t)(i * 16 + li) * CH + kc * 32 + lg * 8);
                short8 wl = *(const short8*)(WQL + (size_t)(i * 16 + li) * CH + kc * 32 + lg * 8);
                accq[i] = __builtin_amdgcn_mfma_f32_16x16x32_bf16(wh, bxw, accq[i], 0, 0, 0);
                accq[i] = __builtin_amdgcn_mfma_f32_16x16x32_bf16(wl, bxw, accq[i], 0, 0, 0);
            }
        }
        float qvv[8];
        float den = 0.f;
        #pragma unroll
        for (int i = 0; i < 2; ++i)
            #pragma unroll
            for (int q = 0; q < 4; ++q) {
                const int m = i * 16 + lg * 4 + q;
                float qv = accq[i][q] + bq[m];
                qv = fmaxf(qv, 0.f) + log1pf(expf(-fabsf(qv)));  // softplus
                qvv[i * 4 + q] = qv;
                den = fmaf(qv, Ksum[b * MDIM + m] + EPSF, den);
            }
        den += __shfl_xor(den, 16);
        den += __shfl_xor(den, 32);
        const float nrm = gk[0] / den;
        #pragma unroll
        for (int i = 0; i < 2; ++i)
            #pragma unroll
            for (int q = 0; q < 4; ++q) {
                const int m = i * 16 + lg * 4 + q;
                qsT[nf * 40 + m] = f2bf(qvv[i * 4 + q] * nrm);
            }
    }
    __syncthreads();

    f32x4 acc[4][4];   // acc[i][j]: rows = n-block j, cols = c-block i
    #pragma unroll
    for (int i = 0; i < 4; ++i)
        #pragma unroll
        for (int j = 0; j < 4; ++j)
            acc[i][j] = (f32x4){0.f, 0.f, 0.f, 0.f};

    // ---- KAM: acc = (nrm·Q)^T · KV  (operand-swapped: rows = n) ----
    {
        short8 qb[4];
        #pragma unroll
        for (int j = 0; j < 4; ++j)
            qb[j] = *(const short8*)&qsT[(j * 16 + li) * 40 + lg * 8];
        #pragma unroll
        for (int i = 0; i < 4; ++i) {
            short8 ka = *(const short8*)(KVTb +
                ((size_t)b * CH + w * 64 + i * 16 + li) * MDIM + lg * 8);
            #pragma unroll
            for (int j = 0; j < 4; ++j)
                acc[i][j] = __builtin_amdgcn_mfma_f32_16x16x32_bf16(qb[j], ka, acc[i][j], 0, 0, 0);
        }
    }

    // ---- CAM: acc += X^T · (gc·attn)^T  (operand-swapped: rows = n) ----
    const unsigned short* ab = attnb + (size_t)b * CH * CH;
    for (int kk = 0; kk < CH; kk += 32) {
        short8 af[4], bx[4];
        #pragma unroll
        for (int i = 0; i < 4; ++i)
            af[i] = *(const short8*)(ab +
                (size_t)(w * 64 + i * 16 + li) * CH + kk + lg * 8);
        #pragma unroll
        for (int j = 0; j < 4; ++j) {
            const int nf = j * 16 + li;
            const int d2 = 2 * (kk + lg * 8);
            const int sw = ((nf & 7) << 4) ^ (((nf >> 3) & 1) << 3);
            uint2 h0 = *(const uint2*)(xsT + nf * 512 + (d2 ^ sw));
            uint2 h1 = *(const uint2*)(xsT + nf * 512 + ((d2 + 8) ^ sw));
            int4 tmp = make_int4(h0.x, h0.y, h1.x, h1.y);
            bx[j] = __builtin_bit_cast(short8, tmp);
        }
        #pragma unroll
        for (int i = 0; i < 4; ++i)
            #pragma unroll
            for (int j = 0; j < 4; ++j)
                acc[i][j] = __builtin_amdgcn_mfma_f32_16x16x32_bf16(bx[j], af[i], acc[i][j], 0, 0, 0);
    }

    // ---- epilogue: out = x + acc, float4 per (i,j): n = n0+j*16+lg*4.. ----
    float* outb = out + (size_t)b * CH * NPIX;
    #pragma unroll
    for (int i = 0; i < 4; ++i) {
        const int c = w * 64 + i * 16 + li;
        #pragma unroll
        for (int j = 0; j < 4; ++j) {
            const size_t idx = (size_t)c * NPIX + n0 + j * 16 + lg * 4;
            float4 xv = *(const float4*)(xb + idx);
            float4 v = make_float4(xv.x + acc[i][j][0], xv.y + acc[i][j][1],
                                   xv.z + acc[i][j][2], xv.w + acc[i][j][3]);
            *(float4*)(outb + idx) = v;
        }
    }
}

extern "C" void kernel_launch(void* const* d_in, const int* in_sizes, int n_in,
                              void* d_out, int out_size, void* d_ws, size_t ws_size,
                              hipStream_t stream)
{
    const float* x  = (const float*)d_in[0];
    const float* wq = (const float*)d_in[1];
    const float* bq = (const float*)d_in[2];
    const float* wk = (const float*)d_in[3];
    const float* bk = (const float*)d_in[4];
    const float* wv = (const float*)d_in[5];
    const float* bv = (const float*)d_in[6];
    const float* gk = (const float*)d_in[7];
    const float* gc = (const float*)d_in[8];
    float* out = (float*)d_out;
    char* wsb = (char*)d_ws;

    unsigned short* ATTB = (unsigned short*)(wsb);
    unsigned short* KVTB = (unsigned short*)(wsb + 1048576);
    float* KSUM = (float*)(wsb + 1179648);
    float* XKR  = (float*)(wsb + 1180672);
    unsigned short* WQH = (unsigned short*)(wsb + 1442816);
    unsigned short* WQL = (unsigned short*)(wsb + 1459200);
    unsigned short* WKH = (unsigned short*)(wsb + 1475584);
    unsigned short* WKL = (unsigned short*)(wsb + 1491968);

    unsigned short* xkpart = (unsigned short*)out;   // d_out scratch (bf16 partials)
    float* enpart = out + XKPART_F32OFF;

    // zero KSUM (1 KB) + XKR (256 KB) — contiguous
    hipMemsetAsync(KSUM, 0, 1024 + 262144, stream);

    k_prep<<<dim3(32), dim3(256), 0, stream>>>(wq, wk, WQH, WQL, WKH, WKL);
    k_kx<<<dim3(NPIX / 64, NB), dim3(256), 0, stream>>>(x, WKH, WKL, bk, xkpart, KSUM);
    k_gram<<<dim3(3, SPLIT, NB), dim3(256), 0, stream>>>(x, enpart);
    k_xkreduce<<<dim3(NB * MDIM, 4), dim3(CH), 0, stream>>>(xkpart, XKR);
    k_kv<<<dim3(NB, 4), dim3(256), 0, stream>>>(wv, bv, XKR, KSUM, KVTB);
    k_softmax<<<dim3(NB * CH), dim3(CH), 0, stream>>>(enpart, gc, ATTB);
    k_final<<<dim3(NPIX / 64, NB), dim3(256), 0, stream>>>(x, WQH, WQL, bq, KVTB, KSUM,
                                                           ATTB, gk, out);
}